// Round 1
// baseline (7937.852 us; speedup 1.0000x reference)
//
#include <hip/hip_runtime.h>
#include <hip/hip_bf16.h>
#include <math.h>

// Problem constants
#define NTOT 4096      // B*N nodes
#define NEDGE 65536    // E edges
#define BSZ 64         // batch (number_of_trajectories)
#define NN 64          // nodes per trajectory
#define FDIM 2         // features
#define HDIM 1024      // LSTM hidden
#define TIN 10
#define TOUT 6
#define FRAME_ELEMS (NTOT * FDIM)   // 8192 floats per output frame

// ---------------- GCN (edge-list form) ----------------

__global__ void init_deg_kernel(float* deg) {
    int i = blockIdx.x * blockDim.x + threadIdx.x;
    if (i < NTOT) deg[i] = 1.0f;   // add_remaining_self_loops: deg starts at 1
}

__global__ void count_edges_kernel(const int* __restrict__ ei, float* deg) {
    int e = blockIdx.x * blockDim.x + threadIdx.x;
    if (e < NEDGE) {
        int d = ei[NEDGE + e];
        atomicAdd(&deg[d], 1.0f);
    }
}

// deg -> dinv (overwrites deg), xw = x @ Wg^T, g = xw * dinv^2 + b
__global__ void gcn_node_kernel(const float* __restrict__ x,
                                const float* __restrict__ wg,
                                const float* __restrict__ bg,
                                float* deg, float* xw, float* g) {
    int i = blockIdx.x * blockDim.x + threadIdx.x;
    if (i >= NTOT) return;
    float d = deg[i];
    float dinv = rsqrtf(d);
    deg[i] = dinv;
    float x0 = x[i * 2], x1 = x[i * 2 + 1];
    float v0 = x0 * wg[0] + x1 * wg[1];
    float v1 = x0 * wg[2] + x1 * wg[3];
    xw[i * 2] = v0;
    xw[i * 2 + 1] = v1;
    g[i * 2]     = v0 * dinv * dinv + bg[0];
    g[i * 2 + 1] = v1 * dinv * dinv + bg[1];
}

__global__ void gcn_scatter_kernel(const int* __restrict__ ei,
                                   const float* __restrict__ dinv,
                                   const float* __restrict__ xw,
                                   float* g) {
    int e = blockIdx.x * blockDim.x + threadIdx.x;
    if (e >= NEDGE) return;
    int s = ei[e];
    int d = ei[NEDGE + e];
    float w = dinv[s] * dinv[d];
    atomicAdd(&g[d * 2],     xw[s * 2] * w);
    atomicAdd(&g[d * 2 + 1], xw[s * 2 + 1] * w);
}

// ---------------- generic matmul: out(64,NO) = act(in(64,K) @ W(NO,K)^T + bias) ----------------
// flags: bit0 = relu, bit1 = accumulate into existing out
__global__ __launch_bounds__(256) void mm_kernel(const float* __restrict__ in,
                                                 const float* __restrict__ W,
                                                 const float* __restrict__ bias,
                                                 float* __restrict__ out,
                                                 int K, int NO, int flags) {
    __shared__ float in_t[64 * 36];   // 64 rows x 32 k, padded to 36
    __shared__ float w_t[16 * 36];    // 16 n-rows x 32 k
    int tx = threadIdx.x;
    int nb = blockIdx.x * 16;
    int m = tx & 63;
    int ng = tx >> 6;   // 0..3
    float acc[4] = {0.f, 0.f, 0.f, 0.f};

    for (int k0 = 0; k0 < K; k0 += 32) {
        // load input tile: 64x32 = 512 float4
        #pragma unroll
        for (int t = 0; t < 2; ++t) {
            int idx = tx + t * 256;            // 0..511
            int row = idx >> 3, kq = idx & 7;
            float4 v = *(const float4*)&in[row * K + k0 + kq * 4];
            *(float4*)&in_t[row * 36 + kq * 4] = v;
        }
        // load W tile: 16x32 = 128 float4
        if (tx < 128) {
            int row = tx >> 3, kq = tx & 7;
            float4 v = *(const float4*)&W[(nb + row) * K + k0 + kq * 4];
            *(float4*)&w_t[row * 36 + kq * 4] = v;
        }
        __syncthreads();
        #pragma unroll
        for (int kq = 0; kq < 8; ++kq) {
            float4 xv = *(const float4*)&in_t[m * 36 + kq * 4];
            #pragma unroll
            for (int j = 0; j < 4; ++j) {
                float4 wv = *(const float4*)&w_t[(ng * 4 + j) * 36 + kq * 4];
                acc[j] += xv.x * wv.x + xv.y * wv.y + xv.z * wv.z + xv.w * wv.w;
            }
        }
        __syncthreads();
    }
    #pragma unroll
    for (int j = 0; j < 4; ++j) {
        int n = nb + ng * 4 + j;
        float v = acc[j] + bias[n];
        if (flags & 2) v += out[m * NO + n];
        if (flags & 1) v = fmaxf(v, 0.0f);
        out[m * NO + n] = v;
    }
}

// ---------------- LSTM pointwise update ----------------
__global__ void lstm_update_kernel(const float* __restrict__ gates,
                                   float* h, float* c) {
    int idx = blockIdx.x * blockDim.x + threadIdx.x;   // 64*1024
    if (idx >= BSZ * HDIM) return;
    int b = idx >> 10, j = idx & 1023;
    const float* gr = gates + b * 4 * HDIM;
    float gi = gr[j];
    float gf = gr[HDIM + j];
    float gg = gr[2 * HDIM + j];
    float go = gr[3 * HDIM + j];
    float si = 1.0f / (1.0f + expf(-gi));
    float sf = 1.0f / (1.0f + expf(-gf));
    float so = 1.0f / (1.0f + expf(-go));
    float cn = sf * c[idx] + si * tanhf(gg);
    c[idx] = cn;
    h[idx] = so * tanhf(cn);
}

// ---------------- dense GCN (decoder steps >= 1) ----------------
__global__ void gcn_dense_kernel(const float* __restrict__ x,
                                 const float* __restrict__ A,
                                 const float* __restrict__ wg,
                                 const float* __restrict__ bg,
                                 float* g) {
    int b = blockIdx.x;
    int i = threadIdx.x;   // 64 threads
    __shared__ float sxw0[NN], sxw1[NN], sdinv[NN];
    const float* Ab = A + b * NN * NN;
    float x0 = x[(b * NN + i) * 2], x1 = x[(b * NN + i) * 2 + 1];
    sxw0[i] = x0 * wg[0] + x1 * wg[1];
    sxw1[i] = x0 * wg[2] + x1 * wg[3];
    float dsum = 0.f;
    for (int j = 0; j < NN; ++j) dsum += Ab[i * NN + j];
    sdinv[i] = dsum > 0.f ? rsqrtf(dsum) : 0.f;
    __syncthreads();
    float a0 = 0.f, a1 = 0.f;
    for (int j = 0; j < NN; ++j) {
        float an = Ab[i * NN + j] * sdinv[j];
        a0 += an * sxw0[j];
        a1 += an * sxw1[j];
    }
    float di = sdinv[i];
    g[(b * NN + i) * 2]     = a0 * di + bg[0];
    g[(b * NN + i) * 2 + 1] = a1 * di + bg[1];
}

// ---------------- adjacency from prediction ----------------
__global__ void build_adj_kernel(const float* __restrict__ pred,
                                 const float* __restrict__ stats,
                                 float* A) {
    int b = blockIdx.x;
    int tx = threadIdx.x;  // 256
    __shared__ float f0[NN], f1[NN];
    __shared__ int ex[NN];
    if (tx < NN) {
        float p0 = pred[(b * NN + tx) * 2]     * stats[0] + stats[2];
        float p1 = pred[(b * NN + tx) * 2 + 1] * stats[1] + stats[3];
        f0[tx] = p0;
        f1[tx] = p1;
        ex[tx] = (p0 > 0.04f) && (p1 > 0.04f);
    }
    __syncthreads();
    for (int idx = tx; idx < NN * NN; idx += 256) {
        int i = idx >> 6, j = idx & 63;
        float dx = f0[i] - f0[j];
        float dy = f1[i] - f1[j];
        float d2 = dx * dx + dy * dy;
        float a = (d2 <= 100.0f && ex[i] && ex[j]) ? 1.0f : 0.0f;
        if (i == j) a = 1.0f;
        A[b * NN * NN + idx] = a;
    }
}

extern "C" void kernel_launch(void* const* d_in, const int* in_sizes, int n_in,
                              void* d_out, int out_size, void* d_ws, size_t ws_size,
                              hipStream_t stream) {
    const float* feat   = (const float*)d_in[0];   // (10, 4096, 2)
    const int*   ei_in  = (const int*)d_in[1];     // (10, 2, 65536)
    const float* stats  = (const float*)d_in[4];   // (2,2)
    const float* w_gcn  = (const float*)d_in[5];
    const float* b_gcn  = (const float*)d_in[6];
    const float* w_ih   = (const float*)d_in[7];   // (4096, 128)
    const float* w_hh   = (const float*)d_in[8];   // (4096, 1024)
    const float* b_ih   = (const float*)d_in[9];
    const float* b_hh   = (const float*)d_in[10];
    const float* wm[6], *bm[6];
    for (int i = 0; i < 6; ++i) { wm[i] = (const float*)d_in[11 + 2*i]; bm[i] = (const float*)d_in[12 + 2*i]; }
    const int mlp_K[6]  = {1024, 2048, 4096, 2048, 1024, 512};
    const int mlp_NO[6] = {2048, 4096, 2048, 1024, 512, 128};

    float* out = (float*)d_out;
    float* ws  = (float*)d_ws;

    // workspace layout (floats)
    float* deg   = ws;                       // 4096
    float* xw    = deg + 4096;               // 8192
    float* g     = xw + 8192;                // 8192
    float* h     = g + 8192;                 // 65536
    float* c     = h + 65536;                // 65536
    float* gates = c + 65536;                // 262144
    float* a1    = gates + 262144;           // 131072
    float* a2    = a1 + 131072;              // 262144
    float* a3    = a2 + 262144;              // 131072
    float* a4    = a3 + 131072;              // 65536
    float* a5    = a4 + 65536;               // 32768
    float* Adj   = a5 + 32768;               // 262144

    // frame 0 of output = feature_input[0]
    hipMemcpyAsync(out, feat, FRAME_ELEMS * sizeof(float), hipMemcpyDeviceToDevice, stream);
    // zero h and c (adjacent)
    hipMemsetAsync(h, 0, 2 * BSZ * HDIM * sizeof(float), stream);

    auto gcn_edges = [&](const float* x, const int* ei) {
        init_deg_kernel<<<NTOT / 256, 256, 0, stream>>>(deg);
        count_edges_kernel<<<NEDGE / 256, 256, 0, stream>>>(ei, deg);
        gcn_node_kernel<<<NTOT / 256, 256, 0, stream>>>(x, w_gcn, b_gcn, deg, xw, g);
        gcn_scatter_kernel<<<NEDGE / 256, 256, 0, stream>>>(ei, deg, xw, g);
    };

    auto lstm_mlp = [&](float* pred_out) {
        // gates = g @ w_ih^T + b_ih  ;  gates += h @ w_hh^T + b_hh
        mm_kernel<<<4096 / 16, 256, 0, stream>>>(g, w_ih, b_ih, gates, 128, 4096, 0);
        mm_kernel<<<4096 / 16, 256, 0, stream>>>(h, w_hh, b_hh, gates, 1024, 4096, 2);
        lstm_update_kernel<<<BSZ * HDIM / 256, 256, 0, stream>>>(gates, h, c);
        // MLP
        const float* cur = h;
        float* bufs[6] = {a1, a2, a3, a4, a5, pred_out};
        for (int l = 0; l < 6; ++l) {
            int fl = (l < 5) ? 1 : 0;   // relu except last
            mm_kernel<<<mlp_NO[l] / 16, 256, 0, stream>>>(cur, wm[l], bm[l], bufs[l], mlp_K[l], mlp_NO[l], fl);
            cur = bufs[l];
        }
    };

    // encoder: frames 0..8
    for (int i = 0; i < TIN - 1; ++i) {
        gcn_edges(feat + i * FRAME_ELEMS, ei_in + i * 2 * NEDGE);
        lstm_mlp(out + (i + 1) * FRAME_ELEMS);
    }

    // decoder
    for (int i = 0; i < TOUT; ++i) {
        if (i == 0) {
            gcn_edges(feat + (TIN - 1) * FRAME_ELEMS, ei_in + (TIN - 1) * 2 * NEDGE);
        } else {
            const float* cur_x = out + (TIN + i - 1) * FRAME_ELEMS;
            gcn_dense_kernel<<<BSZ, NN, 0, stream>>>(cur_x, Adj, w_gcn, b_gcn, g);
        }
        float* pred = out + (TIN + i) * FRAME_ELEMS;
        lstm_mlp(pred);
        if (i < TOUT - 1) {
            build_adj_kernel<<<BSZ, 256, 0, stream>>>(pred, stats, Adj);
        }
    }
}

// Round 2
// 5299.528 us; speedup vs baseline: 1.4978x; 1.4978x over previous
//
#include <hip/hip_runtime.h>
#include <hip/hip_bf16.h>
#include <math.h>

// Problem constants
#define NTOT 4096      // B*N nodes
#define NEDGE 65536    // E edges
#define BSZ 64         // batch
#define NN 64          // nodes per trajectory
#define HDIM 1024      // LSTM hidden
#define TIN 10
#define TOUT 6
#define FRAME_ELEMS (NTOT * 2)   // 8192 floats per frame

// ==================== shared small kernels ====================

__global__ void init_deg_kernel(float* deg) {
    int i = blockIdx.x * blockDim.x + threadIdx.x;
    if (i < NTOT) deg[i] = 1.0f;
}

__global__ void count_edges_kernel(const int* __restrict__ ei, float* deg) {
    int e = blockIdx.x * blockDim.x + threadIdx.x;
    if (e < NEDGE) atomicAdd(&deg[ei[NEDGE + e]], 1.0f);
}

// ---- transposed-activation GCN variants (colwave path) ----
// gT layout: (F*N rows = 128, 64 batch cols): gT[(nn*2+f)*64 + b]
__global__ void gcn_node_T_kernel(const float* __restrict__ x,
                                  const float* __restrict__ wg,
                                  const float* __restrict__ bg,
                                  float* deg, float* xw, float* gT) {
    int i = blockIdx.x * blockDim.x + threadIdx.x;
    if (i >= NTOT) return;
    float d = deg[i];
    float dinv = rsqrtf(d);
    deg[i] = dinv;
    float x0 = x[i * 2], x1 = x[i * 2 + 1];
    float v0 = x0 * wg[0] + x1 * wg[1];
    float v1 = x0 * wg[2] + x1 * wg[3];
    xw[i * 2] = v0;
    xw[i * 2 + 1] = v1;
    int b = i >> 6, nn = i & 63;
    gT[(nn * 2 + 0) * 64 + b] = v0 * dinv * dinv + bg[0];
    gT[(nn * 2 + 1) * 64 + b] = v1 * dinv * dinv + bg[1];
}

__global__ void gcn_scatter_T_kernel(const int* __restrict__ ei,
                                     const float* __restrict__ dinv,
                                     const float* __restrict__ xw,
                                     float* gT) {
    int e = blockIdx.x * blockDim.x + threadIdx.x;
    if (e >= NEDGE) return;
    int s = ei[e];
    int d = ei[NEDGE + e];
    float w = dinv[s] * dinv[d];
    int b = d >> 6, nn = d & 63;
    atomicAdd(&gT[(nn * 2 + 0) * 64 + b], xw[s * 2] * w);
    atomicAdd(&gT[(nn * 2 + 1) * 64 + b], xw[s * 2 + 1] * w);
}

__global__ void gcn_dense_T_kernel(const float* __restrict__ x,   // pred std (4096,2)
                                   const float* __restrict__ A,
                                   const float* __restrict__ wg,
                                   const float* __restrict__ bg,
                                   float* gT) {
    int b = blockIdx.x;
    int i = threadIdx.x;   // 64
    __shared__ float sxw0[NN], sxw1[NN], sdinv[NN];
    const float* Ab = A + b * NN * NN;
    float x0 = x[(b * NN + i) * 2], x1 = x[(b * NN + i) * 2 + 1];
    sxw0[i] = x0 * wg[0] + x1 * wg[1];
    sxw1[i] = x0 * wg[2] + x1 * wg[3];
    float dsum = 0.f;
    for (int j = 0; j < NN; ++j) dsum += Ab[i * NN + j];
    sdinv[i] = dsum > 0.f ? rsqrtf(dsum) : 0.f;
    __syncthreads();
    float a0 = 0.f, a1 = 0.f;
    for (int j = 0; j < NN; ++j) {
        float an = Ab[i * NN + j] * sdinv[j];
        a0 += an * sxw0[j];
        a1 += an * sxw1[j];
    }
    float di = sdinv[i];
    gT[(i * 2 + 0) * 64 + b] = a0 * di + bg[0];
    gT[(i * 2 + 1) * 64 + b] = a1 * di + bg[1];
}

__global__ void build_adj_kernel(const float* __restrict__ pred,
                                 const float* __restrict__ stats,
                                 float* A) {
    int b = blockIdx.x;
    int tx = threadIdx.x;  // 256
    __shared__ float f0[NN], f1[NN];
    __shared__ int ex[NN];
    if (tx < NN) {
        float p0 = pred[(b * NN + tx) * 2]     * stats[0] + stats[2];
        float p1 = pred[(b * NN + tx) * 2 + 1] * stats[1] + stats[3];
        f0[tx] = p0;
        f1[tx] = p1;
        ex[tx] = (p0 > 0.04f) && (p1 > 0.04f);
    }
    __syncthreads();
    for (int idx = tx; idx < NN * NN; idx += 256) {
        int i = idx >> 6, j = idx & 63;
        float dx = f0[i] - f0[j];
        float dy = f1[i] - f1[j];
        float d2 = dx * dx + dy * dy;
        float a = (d2 <= 100.0f && ex[i] && ex[j]) ? 1.0f : 0.0f;
        if (i == j) a = 1.0f;
        A[b * NN * NN + idx] = a;
    }
}

// ==================== colwave path kernels ====================

// W (NO,K) -> WT (K,NO)
__global__ __launch_bounds__(256) void transpose_kernel(const float* __restrict__ W,
                                                        float* __restrict__ WT,
                                                        int NO, int K) {
    __shared__ float t[32][33];
    int k0 = blockIdx.x * 32;
    int n0 = blockIdx.y * 32;
    int tx = threadIdx.x & 31, ty = threadIdx.x >> 5;  // 32 x 8
    #pragma unroll
    for (int i = 0; i < 4; ++i)
        t[ty + i * 8][tx] = W[(size_t)(n0 + ty + i * 8) * K + k0 + tx];
    __syncthreads();
    #pragma unroll
    for (int i = 0; i < 4; ++i)
        WT[(size_t)(k0 + ty + i * 8) * NO + n0 + tx] = t[tx][ty + i * 8];
}

// out^T partials: P[(ks*NO + n)*64 + m] = sum over k-chunk of in[m][k]*W[n][k]
// lane = m (batch row), 32 n-columns per wave, 4 waves per block (128 n).
template<int KC>
__global__ __launch_bounds__(256) void gemm_cw_kernel(const float* __restrict__ inT, // (K,64)
                                                      const float* __restrict__ WT,  // (K,NO)
                                                      float* __restrict__ P,
                                                      int NO) {
    int lane = threadIdx.x & 63;
    int wid = __builtin_amdgcn_readfirstlane(threadIdx.x >> 6);
    int nb = blockIdx.x * 128 + wid * 32;
    int k0 = blockIdx.y * KC;
    float acc[32];
    #pragma unroll
    for (int j = 0; j < 32; ++j) acc[j] = 0.f;
    const float* wp = WT + (size_t)k0 * NO + nb;
    const float* xp = inT + k0 * 64 + lane;
    float x0 = xp[0], x1 = xp[64], x2 = xp[128], x3 = xp[192];
    for (int k = 0; k < KC; k += 4) {
        float xn0 = 0.f, xn1 = 0.f, xn2 = 0.f, xn3 = 0.f;
        if (k + 4 < KC) {
            xn0 = xp[(k + 4) * 64];
            xn1 = xp[(k + 5) * 64];
            xn2 = xp[(k + 6) * 64];
            xn3 = xp[(k + 7) * 64];
        }
        #pragma unroll
        for (int j = 0; j < 32; ++j) acc[j] = fmaf(x0, wp[(size_t)(k + 0) * NO + j], acc[j]);
        #pragma unroll
        for (int j = 0; j < 32; ++j) acc[j] = fmaf(x1, wp[(size_t)(k + 1) * NO + j], acc[j]);
        #pragma unroll
        for (int j = 0; j < 32; ++j) acc[j] = fmaf(x2, wp[(size_t)(k + 2) * NO + j], acc[j]);
        #pragma unroll
        for (int j = 0; j < 32; ++j) acc[j] = fmaf(x3, wp[(size_t)(k + 3) * NO + j], acc[j]);
        x0 = xn0; x1 = xn1; x2 = xn2; x3 = xn3;
    }
    float* pp = P + ((size_t)blockIdx.y * NO + nb) * 64 + lane;
    #pragma unroll
    for (int j = 0; j < 32; ++j) pp[j * 64] = acc[j];
}

// reduce partials + bias (+relu); write aT (NO,64) and optionally a_std (64,NO)
__global__ void reduce_relu_kernel(const float* __restrict__ P,
                                   const float* __restrict__ bias,
                                   float* __restrict__ aT,
                                   float* __restrict__ a_std,
                                   int NO, int SK, int relu) {
    int idx = blockIdx.x * blockDim.x + threadIdx.x;
    if (idx >= NO * 64) return;
    int n = idx >> 6, m = idx & 63;
    float v = bias[n];
    for (int ks = 0; ks < SK; ++ks) v += P[(size_t)ks * NO * 64 + idx];
    if (relu) v = fmaxf(v, 0.f);
    aT[idx] = v;
    if (a_std) a_std[(size_t)m * NO + n] = v;
}

// gates from partials -> h,c update (transposed layouts)
__global__ void lstm_update_cw_kernel(const float* __restrict__ Pih,
                                      const float* __restrict__ Phh,
                                      const float* __restrict__ b_ih,
                                      const float* __restrict__ b_hh,
                                      float* __restrict__ hT,
                                      float* __restrict__ cT,
                                      int SKih, int SKhh) {
    int t = blockIdx.x * blockDim.x + threadIdx.x;   // over 1024*64
    if (t >= HDIM * BSZ) return;
    int j = t >> 6, b = t & 63;
    float g4[4];
    #pragma unroll
    for (int gi = 0; gi < 4; ++gi) {
        int row = j + gi * HDIM;
        float v = b_ih[row] + b_hh[row];
        size_t base = (size_t)row * 64 + b;
        for (int ks = 0; ks < SKih; ++ks) v += Pih[(size_t)ks * 4 * HDIM * 64 + base];
        for (int ks = 0; ks < SKhh; ++ks) v += Phh[(size_t)ks * 4 * HDIM * 64 + base];
        g4[gi] = v;
    }
    float si = 1.f / (1.f + expf(-g4[0]));
    float sf = 1.f / (1.f + expf(-g4[1]));
    float gg = tanhf(g4[2]);
    float so = 1.f / (1.f + expf(-g4[3]));
    float cn = sf * cT[t] + si * gg;
    cT[t] = cn;
    hT[t] = so * tanhf(cn);
}

// ==================== fallback (baseline) kernels ====================

__global__ void gcn_node_kernel(const float* __restrict__ x,
                                const float* __restrict__ wg,
                                const float* __restrict__ bg,
                                float* deg, float* xw, float* g) {
    int i = blockIdx.x * blockDim.x + threadIdx.x;
    if (i >= NTOT) return;
    float d = deg[i];
    float dinv = rsqrtf(d);
    deg[i] = dinv;
    float x0 = x[i * 2], x1 = x[i * 2 + 1];
    float v0 = x0 * wg[0] + x1 * wg[1];
    float v1 = x0 * wg[2] + x1 * wg[3];
    xw[i * 2] = v0;
    xw[i * 2 + 1] = v1;
    g[i * 2]     = v0 * dinv * dinv + bg[0];
    g[i * 2 + 1] = v1 * dinv * dinv + bg[1];
}

__global__ void gcn_scatter_kernel(const int* __restrict__ ei,
                                   const float* __restrict__ dinv,
                                   const float* __restrict__ xw,
                                   float* g) {
    int e = blockIdx.x * blockDim.x + threadIdx.x;
    if (e >= NEDGE) return;
    int s = ei[e];
    int d = ei[NEDGE + e];
    float w = dinv[s] * dinv[d];
    atomicAdd(&g[d * 2],     xw[s * 2] * w);
    atomicAdd(&g[d * 2 + 1], xw[s * 2 + 1] * w);
}

__global__ __launch_bounds__(256) void mm_kernel(const float* __restrict__ in,
                                                 const float* __restrict__ W,
                                                 const float* __restrict__ bias,
                                                 float* __restrict__ out,
                                                 int K, int NO, int flags) {
    __shared__ float in_t[64 * 36];
    __shared__ float w_t[16 * 36];
    int tx = threadIdx.x;
    int nb = blockIdx.x * 16;
    int m = tx & 63;
    int ng = tx >> 6;
    float acc[4] = {0.f, 0.f, 0.f, 0.f};
    for (int k0 = 0; k0 < K; k0 += 32) {
        #pragma unroll
        for (int t = 0; t < 2; ++t) {
            int idx = tx + t * 256;
            int row = idx >> 3, kq = idx & 7;
            float4 v = *(const float4*)&in[row * K + k0 + kq * 4];
            *(float4*)&in_t[row * 36 + kq * 4] = v;
        }
        if (tx < 128) {
            int row = tx >> 3, kq = tx & 7;
            float4 v = *(const float4*)&W[(nb + row) * K + k0 + kq * 4];
            *(float4*)&w_t[row * 36 + kq * 4] = v;
        }
        __syncthreads();
        #pragma unroll
        for (int kq = 0; kq < 8; ++kq) {
            float4 xv = *(const float4*)&in_t[m * 36 + kq * 4];
            #pragma unroll
            for (int j = 0; j < 4; ++j) {
                float4 wv = *(const float4*)&w_t[(ng * 4 + j) * 36 + kq * 4];
                acc[j] += xv.x * wv.x + xv.y * wv.y + xv.z * wv.z + xv.w * wv.w;
            }
        }
        __syncthreads();
    }
    #pragma unroll
    for (int j = 0; j < 4; ++j) {
        int n = nb + ng * 4 + j;
        float v = acc[j] + bias[n];
        if (flags & 2) v += out[m * NO + n];
        if (flags & 1) v = fmaxf(v, 0.0f);
        out[m * NO + n] = v;
    }
}

__global__ void lstm_update_kernel(const float* __restrict__ gates,
                                   float* h, float* c) {
    int idx = blockIdx.x * blockDim.x + threadIdx.x;
    if (idx >= BSZ * HDIM) return;
    int b = idx >> 10, j = idx & 1023;
    const float* gr = gates + b * 4 * HDIM;
    float gi = gr[j];
    float gf = gr[HDIM + j];
    float gg = gr[2 * HDIM + j];
    float go = gr[3 * HDIM + j];
    float si = 1.0f / (1.0f + expf(-gi));
    float sf = 1.0f / (1.0f + expf(-gf));
    float so = 1.0f / (1.0f + expf(-go));
    float cn = sf * c[idx] + si * tanhf(gg);
    c[idx] = cn;
    h[idx] = so * tanhf(cn);
}

__global__ void gcn_dense_kernel(const float* __restrict__ x,
                                 const float* __restrict__ A,
                                 const float* __restrict__ wg,
                                 const float* __restrict__ bg,
                                 float* g) {
    int b = blockIdx.x;
    int i = threadIdx.x;
    __shared__ float sxw0[NN], sxw1[NN], sdinv[NN];
    const float* Ab = A + b * NN * NN;
    float x0 = x[(b * NN + i) * 2], x1 = x[(b * NN + i) * 2 + 1];
    sxw0[i] = x0 * wg[0] + x1 * wg[1];
    sxw1[i] = x0 * wg[2] + x1 * wg[3];
    float dsum = 0.f;
    for (int j = 0; j < NN; ++j) dsum += Ab[i * NN + j];
    sdinv[i] = dsum > 0.f ? rsqrtf(dsum) : 0.f;
    __syncthreads();
    float a0 = 0.f, a1 = 0.f;
    for (int j = 0; j < NN; ++j) {
        float an = Ab[i * NN + j] * sdinv[j];
        a0 += an * sxw0[j];
        a1 += an * sxw1[j];
    }
    float di = sdinv[i];
    g[(b * NN + i) * 2]     = a0 * di + bg[0];
    g[(b * NN + i) * 2 + 1] = a1 * di + bg[1];
}

// ==================== host ====================

extern "C" void kernel_launch(void* const* d_in, const int* in_sizes, int n_in,
                              void* d_out, int out_size, void* d_ws, size_t ws_size,
                              hipStream_t stream) {
    const float* feat   = (const float*)d_in[0];
    const int*   ei_in  = (const int*)d_in[1];
    const float* stats  = (const float*)d_in[4];
    const float* w_gcn  = (const float*)d_in[5];
    const float* b_gcn  = (const float*)d_in[6];
    const float* w_ih   = (const float*)d_in[7];
    const float* w_hh   = (const float*)d_in[8];
    const float* b_ih   = (const float*)d_in[9];
    const float* b_hh   = (const float*)d_in[10];
    const float* wm[6], *bm[6];
    for (int i = 0; i < 6; ++i) { wm[i] = (const float*)d_in[11 + 2*i]; bm[i] = (const float*)d_in[12 + 2*i]; }
    const int mlp_K[6]  = {1024, 2048, 4096, 2048, 1024, 512};
    const int mlp_NO[6] = {2048, 4096, 2048, 1024, 512, 128};

    float* out = (float*)d_out;
    float* ws  = (float*)d_ws;

    // ---------- colwave workspace layout (floats) ----------
    size_t off = 0;
    float* wt_ih = ws + off; off += (size_t)128 * 4096;
    float* wt_hh = ws + off; off += (size_t)1024 * 4096;
    float* wt[6];
    const size_t wt_sz[6] = {(size_t)1024*2048, (size_t)2048*4096, (size_t)4096*2048,
                             (size_t)2048*1024, (size_t)1024*512, (size_t)512*128};
    for (int i = 0; i < 6; ++i) { wt[i] = ws + off; off += wt_sz[i]; }
    float* Pbuf = ws + off; off += 2097152;   // max SK*NO*64
    float* Pih  = ws + off; off += 524288;    // 2*4096*64
    float* gT   = ws + off; off += 8192;
    float* hT   = ws + off; off += 65536;
    float* cT   = ws + off; off += 65536;
    float* aT1  = ws + off; off += 131072;
    float* aT2  = ws + off; off += 262144;
    float* aT3  = ws + off; off += 131072;
    float* aT4  = ws + off; off += 65536;
    float* aT5  = ws + off; off += 32768;
    float* predT= ws + off; off += 8192;
    float* deg  = ws + off; off += 4096;
    float* xw   = ws + off; off += 8192;
    float* Adj  = ws + off; off += 262144;
    size_t need_bytes = off * sizeof(float);

    if (ws_size < need_bytes) {
        // ================= fallback: baseline path =================
        float* f_deg   = ws;
        float* f_xw    = f_deg + 4096;
        float* f_g     = f_xw + 8192;
        float* f_h     = f_g + 8192;
        float* f_c     = f_h + 65536;
        float* f_gates = f_c + 65536;
        float* f_a1    = f_gates + 262144;
        float* f_a2    = f_a1 + 131072;
        float* f_a3    = f_a2 + 262144;
        float* f_a4    = f_a3 + 131072;
        float* f_a5    = f_a4 + 65536;
        float* f_Adj   = f_a5 + 32768;

        hipMemcpyAsync(out, feat, FRAME_ELEMS * sizeof(float), hipMemcpyDeviceToDevice, stream);
        hipMemsetAsync(f_h, 0, 2 * BSZ * HDIM * sizeof(float), stream);

        auto gcn_edges = [&](const float* x, const int* ei) {
            init_deg_kernel<<<NTOT / 256, 256, 0, stream>>>(f_deg);
            count_edges_kernel<<<NEDGE / 256, 256, 0, stream>>>(ei, f_deg);
            gcn_node_kernel<<<NTOT / 256, 256, 0, stream>>>(x, w_gcn, b_gcn, f_deg, f_xw, f_g);
            gcn_scatter_kernel<<<NEDGE / 256, 256, 0, stream>>>(ei, f_deg, f_xw, f_g);
        };
        auto lstm_mlp = [&](float* pred_out) {
            mm_kernel<<<4096 / 16, 256, 0, stream>>>(f_g, w_ih, b_ih, f_gates, 128, 4096, 0);
            mm_kernel<<<4096 / 16, 256, 0, stream>>>(f_h, w_hh, b_hh, f_gates, 1024, 4096, 2);
            lstm_update_kernel<<<BSZ * HDIM / 256, 256, 0, stream>>>(f_gates, f_h, f_c);
            const float* cur = f_h;
            float* bufs[6] = {f_a1, f_a2, f_a3, f_a4, f_a5, pred_out};
            for (int l = 0; l < 6; ++l) {
                mm_kernel<<<mlp_NO[l] / 16, 256, 0, stream>>>(cur, wm[l], bm[l], bufs[l],
                                                              mlp_K[l], mlp_NO[l], l < 5 ? 1 : 0);
                cur = bufs[l];
            }
        };
        for (int i = 0; i < TIN - 1; ++i) {
            gcn_edges(feat + i * FRAME_ELEMS, ei_in + i * 2 * NEDGE);
            lstm_mlp(out + (i + 1) * FRAME_ELEMS);
        }
        for (int i = 0; i < TOUT; ++i) {
            if (i == 0) gcn_edges(feat + (TIN - 1) * FRAME_ELEMS, ei_in + (TIN - 1) * 2 * NEDGE);
            else gcn_dense_kernel<<<BSZ, NN, 0, stream>>>(out + (TIN + i - 1) * FRAME_ELEMS, f_Adj, w_gcn, b_gcn, f_g);
            float* pred = out + (TIN + i) * FRAME_ELEMS;
            lstm_mlp(pred);
            if (i < TOUT - 1) build_adj_kernel<<<BSZ, 256, 0, stream>>>(pred, stats, f_Adj);
        }
        return;
    }

    // ================= colwave path =================
    // pre-transpose all weights: W (NO,K) -> WT (K,NO)
    {
        transpose_kernel<<<dim3(128 / 32, 4096 / 32), 256, 0, stream>>>(w_ih, wt_ih, 4096, 128);
        transpose_kernel<<<dim3(1024 / 32, 4096 / 32), 256, 0, stream>>>(w_hh, wt_hh, 4096, 1024);
        for (int l = 0; l < 6; ++l)
            transpose_kernel<<<dim3(mlp_K[l] / 32, mlp_NO[l] / 32), 256, 0, stream>>>(wm[l], wt[l], mlp_NO[l], mlp_K[l]);
    }

    hipMemcpyAsync(out, feat, FRAME_ELEMS * sizeof(float), hipMemcpyDeviceToDevice, stream);
    hipMemsetAsync(hT, 0, 2 * BSZ * HDIM * sizeof(float), stream);   // hT + cT adjacent

    const int mlp_SK[6] = {8, 8, 16, 16, 8, 8};

    auto gemm = [&](const float* inT_, const float* WT_, float* P_, int NO_, int K_, int SK_) {
        dim3 grid(NO_ / 128, SK_);
        int KC = K_ / SK_;
        if (KC == 64)       gemm_cw_kernel<64><<<grid, 256, 0, stream>>>(inT_, WT_, P_, NO_);
        else if (KC == 128) gemm_cw_kernel<128><<<grid, 256, 0, stream>>>(inT_, WT_, P_, NO_);
        else                gemm_cw_kernel<256><<<grid, 256, 0, stream>>>(inT_, WT_, P_, NO_);
    };

    auto gcn_edges_T = [&](const float* x, const int* ei) {
        init_deg_kernel<<<NTOT / 256, 256, 0, stream>>>(deg);
        count_edges_kernel<<<NEDGE / 256, 256, 0, stream>>>(ei, deg);
        gcn_node_T_kernel<<<NTOT / 256, 256, 0, stream>>>(x, w_gcn, b_gcn, deg, xw, gT);
        gcn_scatter_T_kernel<<<NEDGE / 256, 256, 0, stream>>>(ei, deg, xw, gT);
    };

    float* aTs[6] = {aT1, aT2, aT3, aT4, aT5, predT};

    auto lstm_mlp = [&](float* pred_out) {
        gemm(gT, wt_ih, Pih, 4096, 128, 2);
        gemm(hT, wt_hh, Pbuf, 4096, 1024, 8);
        lstm_update_cw_kernel<<<HDIM * BSZ / 256, 256, 0, stream>>>(Pih, Pbuf, b_ih, b_hh, hT, cT, 2, 8);
        const float* cur = hT;
        for (int l = 0; l < 6; ++l) {
            gemm(cur, wt[l], Pbuf, mlp_NO[l], mlp_K[l], mlp_SK[l]);
            reduce_relu_kernel<<<mlp_NO[l] * 64 / 256, 256, 0, stream>>>(
                Pbuf, bm[l], aTs[l], l == 5 ? pred_out : nullptr, mlp_NO[l], mlp_SK[l], l < 5 ? 1 : 0);
            cur = aTs[l];
        }
    };

    for (int i = 0; i < TIN - 1; ++i) {
        gcn_edges_T(feat + i * FRAME_ELEMS, ei_in + i * 2 * NEDGE);
        lstm_mlp(out + (i + 1) * FRAME_ELEMS);
    }
    for (int i = 0; i < TOUT; ++i) {
        if (i == 0) gcn_edges_T(feat + (TIN - 1) * FRAME_ELEMS, ei_in + (TIN - 1) * 2 * NEDGE);
        else gcn_dense_T_kernel<<<BSZ, NN, 0, stream>>>(out + (TIN + i - 1) * FRAME_ELEMS, Adj, w_gcn, b_gcn, gT);
        float* pred = out + (TIN + i) * FRAME_ELEMS;
        lstm_mlp(pred);
        if (i < TOUT - 1) build_adj_kernel<<<BSZ, 256, 0, stream>>>(pred, stats, Adj);
    }
}